// Round 9
// baseline (335.697 us; speedup 1.0000x reference)
//
#include <hip/hip_runtime.h>
#include <hip/hip_bf16.h>
#include <math.h>

// Problem constants
#define FPD 96      // frame size
#define DPD 28      // digit/kernel size
#define CPD 69      // FPD - DPD + 1
#define NPD 4761    // CPD*CPD
#define KKC 3       // K iterations
#define SBN 256     // S*B images
#define TT 8        // T
#define HD 512      // H
#define ZDD 2
#define KP2 5120    // padded K: half0 [0,2560) holds oy<35 (2415 real), half1 [2560,5120) holds oy>=35 (2346 real)
#define HALFK 2560
#define SPLITK 16   // 16 z-blocks x 10 steps x 32 = 5120; z<8 half0, z>=8 half1
#define FRSH 104    // frame LDS row stride (halfs): 52 words, mod32=20 -> conflict-free
#define CVS 76      // cv slab row stride (floats): mod32=12 -> conflict-free

typedef __attribute__((ext_vector_type(8))) short bf16x8;
typedef __attribute__((ext_vector_type(4))) float f32x4;
typedef _Float16 half_t;
typedef __attribute__((ext_vector_type(2))) _Float16 half2_t;

__device__ __forceinline__ float bf2f_lo(unsigned int u) {
    union { unsigned int i; float f; } v; v.i = u << 16; return v.f;
}
__device__ __forceinline__ float bf2f_hi(unsigned int u) {
    union { unsigned int i; float f; } v; v.i = u & 0xffff0000u; return v.f;
}
__device__ __forceinline__ half2_t u2h(unsigned int u) {
    union { unsigned int i; half2_t h; } v; v.i = u; return v.h;
}

// Half-image conv LDS (~63.6 KB -> 2 blocks/CU: the occupancy lever).
// kr/dg start at byte 12896, disjoint from MlpLds (<4200) so they can be
// staged BEFORE the MLP phase runs in the union.
struct ConvLds {
    half_t fr[62 * FRSH];     // 12896 B: 62 frame rows (35 oy + 27 overlap)
    half_t kr[28 * 32];       // 1792 B
    float  dg[2][784];        // 6272 B
    float  cv[4][35 * CVS];   // 42560 B
    float  red[32];           // 128 B
};

struct MlpLds {
    float hsh[HD];
    float h2[2][256];
    float res_sh[2][2];
};

// Bilinear recon value of digit dg placed at (zx,zy), sampled at pixel (r,c).
__device__ __forceinline__ float recon_val(
    const float* __restrict__ dg, float zx, float zy, int r, int c)
{
    const float scale = 96.f / 28.f;
    float oci = (2.f * r + 1.f) / 96.f - 1.f;
    float ocj = (2.f * c + 1.f) / 96.f - 1.f;
    float py = ((scale * (oci - zy) + 1.f) * 28.f - 1.f) * 0.5f;
    float px = ((scale * (ocj - zx) + 1.f) * 28.f - 1.f) * 0.5f;
    float py0f = floorf(py), px0f = floorf(px);
    float fy = py - py0f, fx = px - px0f;
    int y0 = (int)py0f, x0 = (int)px0f;
    int y1 = y0 + 1, x1 = x0 + 1;
    float wy0 = (y0 >= 0 && y0 < DPD) ? 1.f - fy : 0.f;
    float wy1 = (y1 >= 0 && y1 < DPD) ? fy : 0.f;
    float wx0 = (x0 >= 0 && x0 < DPD) ? 1.f - fx : 0.f;
    float wx1 = (x1 >= 0 && x1 < DPD) ? fx : 0.f;
    int y0c = min(max(y0, 0), DPD - 1), y1c = min(max(y1, 0), DPD - 1);
    int x0c = min(max(x0, 0), DPD - 1), x1c = min(max(x1, 0), DPD - 1);
    float tmp0 = wy0 * dg[y0c * DPD + x0c] + wy1 * dg[y1c * DPD + x0c];
    float tmp1 = wy0 * dg[y0c * DPD + x1c] + wy1 * dg[y1c * DPD + x1c];
    return wx0 * tmp0 + wx1 * tmp1;
}

__device__ __forceinline__ void stage_kernel_rows(
    ConvLds& L, const float* __restrict__ ck, int ib, int k, int t)
{
    if (t < 28 * 32) {
        int dy = t >> 5, dx = t & 31;
        float v = (dx < 28) ? ck[((size_t)ib * KKC + k) * 784 + dy * 28 + dx] : 0.f;
        L.kr[t] = (half_t)v;
    }
}

// ---------------------------------------------------------------------------
// Half-image conv: block handles oy in [roy0, roy0+oycnt). Frame values in
// pf[6] registers (guarded by lim), kr/dg pre-staged in LDS.
// Writes exp(v - M_half) to e_buf (half-local k range) and (M_half, S_half)
// to stats_w[ib*4 + half*2 .. +1]. Dot loop = verified round-7 W/V/K form.
template<int NREC>
__device__ __forceinline__ void conv_rest(
    ConvLds& L, int ib, int half, int t,
    const float* __restrict__ pf,
    float z0x, float z0y, float z1x, float z1y,
    ushort* __restrict__ e_buf, float* __restrict__ stats_w)
{
    half_t* fr  = L.fr;
    float*  red = L.red;
    const int roy0  = half ? 35 : 0;
    const int nrows = half ? 61 : 62;
    const int oycnt = half ? 34 : 35;
    const int lim   = nrows * 96;

    #pragma unroll
    for (int i = 0; i < 6; ++i) {
        int p = t + i * 1024;
        if (p < lim) {
            int lr = p / 96, c = p - lr * 96;
            int r = roy0 + lr;
            float val = pf[i];
            if (NREC >= 1) val -= recon_val(L.dg[0], z0x, z0y, r, c);
            if (NREC >= 2) val -= recon_val(L.dg[1], z1x, z1y, r, c);
            fr[lr * FRSH + c] = (half_t)val;
        }
    }
    if (t < 62 * 8) fr[(t >> 3) * FRSH + 96 + (t & 7)] = (half_t)0.f; // pad cols
    __syncthreads();

    const int NT = 12 * oycnt;           // 420 (half0) / 408 (half1)
    if (t < NT) {
        const int q    = t / (3 * oycnt);
        const int rem  = t - q * (3 * oycnt);
        const int tile = rem / oycnt;
        const int oyl  = rem - tile * oycnt;
        const int ox0  = tile * 24;
        const int dy0  = q * 7;

        float acc[24];
        #pragma unroll
        for (int j = 0; j < 24; ++j) acc[j] = 0.f;

        #pragma unroll 1
        for (int dd = 0; dd < 7; ++dd) {
            const int dy = dy0 + dd;
            const unsigned int* frow = (const unsigned int*)&fr[(oyl + dy) * FRSH + ox0];
            const unsigned int* krow = (const unsigned int*)&L.kr[dy * 32];
            unsigned int W[28], K[16], V[25];
            #pragma unroll
            for (int u = 0; u < 7; ++u) {
                uint4 v = *(const uint4*)(frow + 4 * u);
                W[4*u] = v.x; W[4*u+1] = v.y; W[4*u+2] = v.z; W[4*u+3] = v.w;
            }
            #pragma unroll
            for (int u = 0; u < 4; ++u) {
                uint4 v = *(const uint4*)(krow + 4 * u);
                K[4*u] = v.x; K[4*u+1] = v.y; K[4*u+2] = v.z; K[4*u+3] = v.w;
            }
            #pragma unroll
            for (int i = 0; i < 25; ++i)
                V[i] = (W[i] >> 16) | (W[i + 1] << 16);
            #pragma unroll
            for (int m = 0; m < 12; ++m) {
                float ae = acc[2*m], ao = acc[2*m+1];
                #pragma unroll
                for (int i = 0; i < 14; ++i) {
                    ae = __builtin_amdgcn_fdot2(u2h(W[m + i]), u2h(K[i]), ae, false);
                    ao = __builtin_amdgcn_fdot2(u2h(V[m + i]), u2h(K[i]), ao, false);
                }
                acc[2*m] = ae; acc[2*m+1] = ao;
            }
        }
        float* cvq = &L.cv[q][oyl * CVS + ox0];
        #pragma unroll
        for (int u = 0; u < 6; ++u) {
            float4 v = make_float4(acc[4*u], acc[4*u+1], acc[4*u+2], acc[4*u+3]);
            *(float4*)(cvq + 4 * u) = v;
        }
    }
    __syncthreads();

    // merge quarters + half-block max
    const int nele = oycnt * CVS;
    float m = -INFINITY;
    for (int p = t; p < nele; p += 1024) {
        int ox = p - (p / CVS) * CVS;
        if (ox < CPD) {
            float v = L.cv[0][p] + L.cv[1][p] + L.cv[2][p] + L.cv[3][p];
            L.cv[0][p] = v;
            m = fmaxf(m, v);
        }
    }
    #pragma unroll
    for (int off = 32; off > 0; off >>= 1) m = fmaxf(m, __shfl_down(m, off, 64));
    int lane = t & 63, wid = t >> 6;
    if (lane == 0) red[wid] = m;
    __syncthreads();
    m = red[0];
    #pragma unroll
    for (int i = 1; i < 16; ++i) m = fmaxf(m, red[i]);

    // exp relative to half max; write to half-local k range
    const int kbase = half ? HALFK : 0;
    float s = 0.f;
    ushort* eo = e_buf + (size_t)ib * KP2;
    for (int p = t; p < nele; p += 1024) {
        int oyl = p / CVS;
        int ox = p - oyl * CVS;
        if (ox < CPD) {
            float ev = __expf(L.cv[0][p] - m);
            __hip_bfloat16 h = __float2bfloat16(ev);
            eo[kbase + oyl * 69 + ox] = *reinterpret_cast<ushort*>(&h);
            s += ev;
        }
    }
    #pragma unroll
    for (int off = 32; off > 0; off >>= 1) s += __shfl_down(s, off, 64);
    if (lane == 0) red[16 + wid] = s;
    __syncthreads();
    if (t == 0) {
        float tot = 0.f;
        #pragma unroll
        for (int i = 0; i < 16; ++i) tot += red[16 + i];
        stats_w[ib * 4 + half * 2]     = m;     // M_half
        stats_w[ib * 4 + half * 2 + 1] = tot;   // S_half
    }
    // zero this half's k padding
    const int padbase = half ? (HALFK + 34 * 69) : (35 * 69);   // 4906 : 2415
    const int padcnt  = half ? (KP2 - (HALFK + 34 * 69)) : (HALFK - 35 * 69); // 214 : 145
    if (t < padcnt) eo[padbase + t] = 0;
}

// ---------------------------------------------------------------------------
// MLP phase; csum (scaled split-K sum), invd, bias prefetched by caller.
__device__ __forceinline__ void mlp_phase(
    MlpLds& L, int km, int ib, int t,
    float csum, float invd, float b1v,
    const ushort* __restrict__ WhidT,
    const float* __restrict__ bm1, const float* __restrict__ bs1,
    const float* __restrict__ Wm2, const float* __restrict__ bm2,
    const float* __restrict__ Ws2, const float* __restrict__ bs2,
    const float* __restrict__ eps, float* __restrict__ out,
    float* z_keep)
{
    if (t < HD)
        L.hsh[t] = fmaxf(fmaf(csum, invd, b1v), 0.f);
    __syncthreads();

    if (t < 512) {
        int head = t >> 8, col = t & 255;
        const uint4* Wr = (const uint4*)(WhidT + (size_t)(head * 256 + col) * 512);
        float bias = head ? bs1[col] : bm1[col];
        float a = 0.f;
        #pragma unroll 8
        for (int u = 0; u < 64; ++u) {
            uint4 wv = Wr[u];
            const float* hp = &L.hsh[u * 8];
            a = fmaf(hp[0], bf2f_lo(wv.x), a);
            a = fmaf(hp[1], bf2f_hi(wv.x), a);
            a = fmaf(hp[2], bf2f_lo(wv.y), a);
            a = fmaf(hp[3], bf2f_hi(wv.y), a);
            a = fmaf(hp[4], bf2f_lo(wv.z), a);
            a = fmaf(hp[5], bf2f_hi(wv.z), a);
            a = fmaf(hp[6], bf2f_lo(wv.w), a);
            a = fmaf(hp[7], bf2f_hi(wv.w), a);
        }
        L.h2[head][col] = fmaxf(a + bias, 0.f);
    }
    __syncthreads();

    {
        int w = t >> 6, l = t & 63;
        if (w < 4) {
            int zd = (w >> 1) & 1, head = w & 1;
            const float* W2 = head ? Ws2 : Wm2;
            float a = 0.f;
            #pragma unroll
            for (int u = 0; u < 4; ++u) {
                int i = l + u * 64;
                a = fmaf(L.h2[head][i], W2[i * 2 + zd], a);
            }
            #pragma unroll
            for (int off = 32; off > 0; off >>= 1) a += __shfl_down(a, off, 64);
            if (l == 0) {
                float r = head ? __expf(a + bs2[zd]) : tanhf(a + bm2[zd]);
                L.res_sh[zd][head] = r;
            }
        }
    }
    __syncthreads();
    if (t < 2) {
        int zd = t;
        float mean = L.res_sh[zd][0];
        float stdv = L.res_sh[zd][1];
        float ev = eps[(size_t)ib * 6 + km * 2 + zd];
        float z = fmaf(stdv, ev, mean);
        int oidx = ib * 6 + km * 2 + zd;
        out[oidx]        = mean;   // q_mean
        out[1536 + oidx] = stdv;   // q_std
        out[3072 + oidx] = z;      // z_where
        z_keep[zd] = z;            // block-local handoff to fused conv
    }
}

// Combine half-stats + split-K Cpart into csum/invd (exact softmax rescale).
__device__ __forceinline__ void mlp_inputs(
    const float* __restrict__ Cpart, const float* __restrict__ stats_r,
    const float* __restrict__ b1, int ib, int t,
    float& csum, float& invd, float& b1v)
{
    float c0 = 0.f, c1 = 0.f;
    b1v = 0.f;
    if (t < HD) {
        #pragma unroll
        for (int z = 0; z < 8; ++z)
            c0 += Cpart[((size_t)ib * SPLITK + z) * HD + t];
        #pragma unroll
        for (int z = 8; z < 16; ++z)
            c1 += Cpart[((size_t)ib * SPLITK + z) * HD + t];
        b1v = b1[t];
    }
    float M0 = stats_r[ib * 4 + 0], S0 = stats_r[ib * 4 + 1];
    float M1 = stats_r[ib * 4 + 2], S1 = stats_r[ib * 4 + 3];
    float M  = fmaxf(M0, M1);
    float f0 = __expf(M0 - M), f1 = __expf(M1 - M);
    invd = 1.f / fmaf(S0, f0, S1 * f1);
    csum = fmaf(c0, f0, c1 * f1);
}

// ---------------------------------------------------------------------------
// Dispatch 1: conv(k=0) on 512 half-blocks + weight-prep tail.
__global__ __launch_bounds__(1024, 8) void conv0_wprep_kernel(
    const float* __restrict__ frames, const int* __restrict__ tsp,
    const float* __restrict__ ck,
    ushort* __restrict__ e_buf, float* __restrict__ stats0,
    const float* __restrict__ W1, const float* __restrict__ Wm1,
    const float* __restrict__ Ws1,
    ushort* __restrict__ W1T, ushort* __restrict__ WhidT)
{
    __shared__ union __align__(16) {
        ConvLds conv;
        ushort wp[4][64][65];
    } sh;
    const int t    = threadIdx.x;
    const int ibh  = blockIdx.x;     // 0..511
    const int ib   = ibh >> 1;
    const int half = ibh & 1;

    // prefetch: half-frame -> regs, kernel row -> LDS
    const int roy0 = half ? 35 : 0;
    const int lim  = (half ? 61 : 62) * 96;
    const float* src = frames + ((size_t)ib * TT + *tsp) * 9216 + roy0 * 96;
    float pf[6];
    #pragma unroll
    for (int i = 0; i < 6; ++i) {
        int p = t + i * 1024;
        pf[i] = (p < lim) ? src[p] : 0.f;
    }
    stage_kernel_rows(sh.conv, ck, ib, 0, t);
    __syncthreads();   // kr visible before conv dot

    conv_rest<0>(sh.conv, ib, half, t, pf, 0.f, 0.f, 0.f, 0.f, e_buf, stats0);
    __syncthreads();   // conv LDS dead; reuse union for wprep

    {
        const int g  = t >> 8;          // group 0..3
        const int tt = t & 255;
        const int ln = tt & 63;
        const int lr = tt >> 6;         // 0..3
        const int b  = ibh * 4 + g;     // task id: 640 W1T + 64 Whid = 704
        ushort (*tile)[65] = sh.wp[g];

        if (b < 640) {
            const int k0 = (b % 80) * 64;
            const int n0 = (b / 80) * 64;
            #pragma unroll
            for (int i = 0; i < 16; ++i) {
                int kk = k0 + lr + i * 4;
                // k remap: [0,2415) -> np=kk; [2560,4906) -> np=kk-145; else 0
                int np = (kk < HALFK) ? kk : kk - 145;
                bool ok = (kk < 2415) || (kk >= HALFK && kk < 4906);
                float v = ok ? W1[(size_t)np * HD + n0 + ln] : 0.f;
                __hip_bfloat16 h = __float2bfloat16(v);
                tile[lr + i * 4][ln] = *reinterpret_cast<ushort*>(&h);
            }
        } else if (b < 704) {
            const int bb = b - 640;
            const int i0 = (bb & 7) * 64;
            const int r0 = (bb >> 3) * 64;
            #pragma unroll
            for (int rep = 0; rep < 16; ++rep) {
                int i = i0 + lr + rep * 4;
                int r = r0 + ln;
                const float* srcp = (r >= 256) ? Ws1 : Wm1;
                float v = srcp[(size_t)i * 256 + (r & 255)];
                __hip_bfloat16 h = __float2bfloat16(v);
                tile[lr + rep * 4][ln] = *reinterpret_cast<ushort*>(&h);
            }
        }
        __syncthreads();
        if (b < 640) {
            const int k0 = (b % 80) * 64;
            const int n0 = (b / 80) * 64;
            #pragma unroll
            for (int i = 0; i < 16; ++i) {
                int nn = lr + i * 4;
                int kk = k0 + ln;
                W1T[(size_t)(n0 + nn) * KP2 + kk] = tile[ln][nn];
            }
        } else if (b < 704) {
            const int bb = b - 640;
            const int i0 = (bb & 7) * 64;
            const int r0 = (bb >> 3) * 64;
            #pragma unroll
            for (int rep = 0; rep < 16; ++rep) {
                int r = r0 + lr + rep * 4;
                WhidT[(size_t)r * 512 + i0 + ln] = tile[ln][lr + rep * 4];
            }
        }
    }
}

// ---------------------------------------------------------------------------
// Cpart = E @ W1T^T, split-K=16 (uniform 10 steps), register-direct MFMA.
// 1-wave blocks, 2-deep named ping-pong prefetch. Cpart layout [m][z][n].
#define GLOADSET(A,B0,B1,B2,B3,OFF)                        \
    A  = *(const bf16x8*)(pA + (OFF));                     \
    B0 = *(const bf16x8*)(pB + (OFF));                     \
    B1 = *(const bf16x8*)(pB + 16 * KP2 + (OFF));          \
    B2 = *(const bf16x8*)(pB + 32 * KP2 + (OFF));          \
    B3 = *(const bf16x8*)(pB + 48 * KP2 + (OFF));

__global__ __launch_bounds__(64) void gemm1_mfma(
    const ushort* __restrict__ E, const ushort* __restrict__ W1T,
    float* __restrict__ Cpart)
{
    const int t  = threadIdx.x;       // 0..63
    const int bx = blockIdx.x;        // 16 m-panels
    const int n0 = blockIdx.y * 64;   // 8
    const int z  = blockIdx.z;        // 16

    const int lm = t & 15;
    const int kb = (t & 63) >> 4;     // 0..3

    f32x4 zero = {0.f, 0.f, 0.f, 0.f};
    f32x4 acc[4] = {zero, zero, zero, zero};

    const ushort* pA = E   + (size_t)(bx * 16 + lm) * KP2 + kb * 8;
    const ushort* pB = W1T + (size_t)(n0 + lm) * KP2 + kb * 8;
    const int kk0 = z * 320;          // 10 steps x 32

    bf16x8 a0, b00, b01, b02, b03;    // even steps
    bf16x8 a1, b10, b11, b12, b13;    // odd steps
    GLOADSET(a0, b00, b01, b02, b03, kk0)
    GLOADSET(a1, b10, b11, b12, b13, kk0 + 32)

    #pragma unroll 1
    for (int s = 0; s < 10; s += 2) {
        bf16x8 ca = a0, c0 = b00, c1 = b01, c2 = b02, c3 = b03;
        if (s + 2 < 10) { int kn = kk0 + (s + 2) * 32;
            GLOADSET(a0, b00, b01, b02, b03, kn) }
        acc[0] = __builtin_amdgcn_mfma_f32_16x16x32_bf16(ca, c0, acc[0], 0, 0, 0);
        acc[1] = __builtin_amdgcn_mfma_f32_16x16x32_bf16(ca, c1, acc[1], 0, 0, 0);
        acc[2] = __builtin_amdgcn_mfma_f32_16x16x32_bf16(ca, c2, acc[2], 0, 0, 0);
        acc[3] = __builtin_amdgcn_mfma_f32_16x16x32_bf16(ca, c3, acc[3], 0, 0, 0);

        bf16x8 da = a1, d0 = b10, d1 = b11, d2 = b12, d3 = b13;
        if (s + 3 < 10) { int kn = kk0 + (s + 3) * 32;
            GLOADSET(a1, b10, b11, b12, b13, kn) }
        acc[0] = __builtin_amdgcn_mfma_f32_16x16x32_bf16(da, d0, acc[0], 0, 0, 0);
        acc[1] = __builtin_amdgcn_mfma_f32_16x16x32_bf16(da, d1, acc[1], 0, 0, 0);
        acc[2] = __builtin_amdgcn_mfma_f32_16x16x32_bf16(da, d2, acc[2], 0, 0, 0);
        acc[3] = __builtin_amdgcn_mfma_f32_16x16x32_bf16(da, d3, acc[3], 0, 0, 0);
    }

    // C/D layout: col = lane&15 (n), row = (lane>>4)*4 + reg (m)
    const int mrow = bx * 16 + kb * 4;
    #pragma unroll
    for (int j = 0; j < 4; ++j) {
        int n = n0 + j * 16 + lm;
        #pragma unroll
        for (int rg = 0; rg < 4; ++rg)
            Cpart[((size_t)(mrow + rg) * SPLITK + z) * HD + n] = acc[j][rg];
    }
}

// ---------------------------------------------------------------------------
// Dispatch 3/5: mlp(KM) + conv(KM+1) on 512 half-blocks.
// MLP is duplicated per half (identical outputs; benign racing writes).
// stats double-buffered by k parity (stats_r = k=KM buffer, stats_w = k=KM+1)
// so the cross-half WAR hazard (one half reads while the other writes) can't
// occur. KM=1 conv subtracts both recons straight from frames (no frameL).
template<int KM>
__global__ __launch_bounds__(1024, 8) void mlp_conv_kernel(
    const float* __restrict__ Cpart, const float* __restrict__ stats_r,
    float* __restrict__ stats_w,
    const float* __restrict__ b1, const ushort* __restrict__ WhidT,
    const float* __restrict__ bm1, const float* __restrict__ bs1,
    const float* __restrict__ Wm2, const float* __restrict__ bm2,
    const float* __restrict__ Ws2, const float* __restrict__ bs2,
    const float* __restrict__ eps, float* __restrict__ out,
    const float* __restrict__ frames, const int* __restrict__ tsp,
    const float* __restrict__ ck, ushort* __restrict__ e_buf)
{
    __shared__ union __align__(16) {
        ConvLds conv;
        MlpLds  mlp;
    } sh;
    __shared__ float z_keep[2];
    const int t    = threadIdx.x;
    const int ibh  = blockIdx.x;     // 0..511
    const int ib   = ibh >> 1;
    const int half = ibh & 1;

    // ---- prefetch phase (all inputs ready at kernel entry) ----
    const int roy0 = half ? 35 : 0;
    const int lim  = (half ? 61 : 62) * 96;
    const float* src = frames + ((size_t)ib * TT + *tsp) * 9216 + roy0 * 96;
    float pf[6];
    #pragma unroll
    for (int i = 0; i < 6; ++i) {
        int p = t + i * 1024;
        pf[i] = (p < lim) ? src[p] : 0.f;
    }
    // conv filter row + digit(s) -> LDS (disjoint from MlpLds; MLP's internal
    // barriers order these stores before conv consumes them)
    stage_kernel_rows(sh.conv, ck, ib, KM + 1, t);
    if (t < 784) {
        sh.conv.dg[0][t] = ck[((size_t)ib * KKC + 0) * 784 + t];
        if (KM == 1)
            sh.conv.dg[1][t] = ck[((size_t)ib * KKC + 1) * 784 + t];
    }
    // z of iteration 0 (written to out by the previous mlp_conv dispatch)
    float z0x = 0.f, z0y = 0.f;
    if (KM == 1) {
        z0x = out[3072 + ib * 6 + 0];
        z0y = out[3072 + ib * 6 + 1];
    }
    float csum, invd, b1v;
    mlp_inputs(Cpart, stats_r, b1, ib, t, csum, invd, b1v);

    // ---- MLP (uses only MlpLds region) ----
    mlp_phase(sh.mlp, KM, ib, t, csum, invd, b1v, WhidT,
              bm1, bs1, Wm2, bm2, Ws2, bs2, eps, out, z_keep);
    __syncthreads();   // mlp LDS dead; z_keep visible to all

    float zkx = z_keep[0], zky = z_keep[1];
    if (KM == 0) {
        conv_rest<1>(sh.conv, ib, half, t, pf, zkx, zky, 0.f, 0.f,
                     e_buf, stats_w);
    } else {
        conv_rest<2>(sh.conv, ib, half, t, pf, z0x, z0y, zkx, zky,
                     e_buf, stats_w);
    }
}

// ---------------------------------------------------------------------------
// Dispatch 7: final mlp (km=2), standalone, 256 blocks.
__global__ __launch_bounds__(512) void mlp_final_kernel(
    const float* __restrict__ Cpart, const float* __restrict__ stats_r,
    const float* __restrict__ b1, const ushort* __restrict__ WhidT,
    const float* __restrict__ bm1, const float* __restrict__ bs1,
    const float* __restrict__ Wm2, const float* __restrict__ bm2,
    const float* __restrict__ Ws2, const float* __restrict__ bs2,
    const float* __restrict__ eps, float* __restrict__ out)
{
    __shared__ MlpLds L;
    __shared__ float z_keep[2];
    const int t  = threadIdx.x;
    const int ib = blockIdx.x;
    float csum, invd, b1v;
    mlp_inputs(Cpart, stats_r, b1, ib, t, csum, invd, b1v);
    mlp_phase(L, 2, ib, t, csum, invd, b1v, WhidT,
              bm1, bs1, Wm2, bm2, Ws2, bs2, eps, out, z_keep);
}

// ---------------------------------------------------------------------------
extern "C" void kernel_launch(void* const* d_in, const int* in_sizes, int n_in,
                              void* d_out, int out_size, void* d_ws, size_t ws_size,
                              hipStream_t stream)
{
    const float* frames = (const float*)d_in[0];
    const float* ck     = (const float*)d_in[1];
    const float* eps    = (const float*)d_in[2];
    const float* W1     = (const float*)d_in[3];
    const float* b1     = (const float*)d_in[4];
    const float* Wm1    = (const float*)d_in[5];
    const float* bm1    = (const float*)d_in[6];
    const float* Wm2    = (const float*)d_in[7];
    const float* bm2    = (const float*)d_in[8];
    const float* Ws1    = (const float*)d_in[9];
    const float* bs1    = (const float*)d_in[10];
    const float* Ws2    = (const float*)d_in[11];
    const float* bs2    = (const float*)d_in[12];
    const int*   tsp    = (const int*)d_in[13];
    float* out = (float*)d_out;

    float* Cpart   = (float*)d_ws;                   // 256*16*512 = 2097152 f
    float* statsA  = Cpart + 2097152;                 // 1024 f (k even)
    float* statsB  = statsA + 1024;                   // 1024 f (k odd)
    ushort* e_buf  = (ushort*)(statsB + 1024);        // 256*KP2
    ushort* W1T    = e_buf + (size_t)SBN * KP2;       // 512*KP2
    ushort* WhidT  = W1T + (size_t)HD * KP2;          // 512*512

    // D1: conv k=0 on 512 half-blocks (+ wprep tail) -> statsA
    conv0_wprep_kernel<<<512, 1024, 0, stream>>>(
        frames, tsp, ck, e_buf, statsA, W1, Wm1, Ws1, W1T, WhidT);
    // D2: gemm k=0
    gemm1_mfma<<<dim3(16, 8, SPLITK), 64, 0, stream>>>(e_buf, W1T, Cpart);
    // D3: mlp k=0 (reads statsA) + conv k=1 (writes statsB)
    mlp_conv_kernel<0><<<512, 1024, 0, stream>>>(
        Cpart, statsA, statsB, b1, WhidT, bm1, bs1, Wm2, bm2, Ws2, bs2,
        eps, out, frames, tsp, ck, e_buf);
    // D4: gemm k=1
    gemm1_mfma<<<dim3(16, 8, SPLITK), 64, 0, stream>>>(e_buf, W1T, Cpart);
    // D5: mlp k=1 (reads statsB) + conv k=2 (writes statsA)
    mlp_conv_kernel<1><<<512, 1024, 0, stream>>>(
        Cpart, statsB, statsA, b1, WhidT, bm1, bs1, Wm2, bm2, Ws2, bs2,
        eps, out, frames, tsp, ck, e_buf);
    // D6: gemm k=2
    gemm1_mfma<<<dim3(16, 8, SPLITK), 64, 0, stream>>>(e_buf, W1T, Cpart);
    // D7: mlp k=2 (reads statsA)
    mlp_final_kernel<<<256, 512, 0, stream>>>(
        Cpart, statsA, b1, WhidT, bm1, bs1, Wm2, bm2, Ws2, bs2, eps, out);
}